// Round 3
// baseline (277.303 us; speedup 1.0000x reference)
//
#include <hip/hip_runtime.h>

typedef __attribute__((ext_vector_type(8))) short short8;
typedef __attribute__((ext_vector_type(4))) short short4v;
typedef __attribute__((ext_vector_type(4))) float floatx4;

__device__ __forceinline__ unsigned short f2b(float f) {
    union { float f; unsigned int i; } v; v.f = f;
    unsigned int u = v.i;
    u += 0x7FFFu + ((u >> 16) & 1u);   // round-nearest-even; no NaNs in this data
    return (unsigned short)(u >> 16);
}

// ---- kernel 1: W fp32 -> bf16 into workspace (16384 elements) ----
__global__ __launch_bounds__(256) void convert_w_kernel(
    const float* __restrict__ W, unsigned short* __restrict__ Wb)
{
    int i = (blockIdx.x * 256 + threadIdx.x) * 4;
    floatx4 w = *reinterpret_cast<const floatx4*>(W + i);
    short4v p;
#pragma unroll
    for (int j = 0; j < 4; ++j) p[j] = (short)f2b(w[j]);
    *reinterpret_cast<short4v*>(Wb + i) = p;
}

// ---- kernel 2: fused mobius linear ----
// 4 waves/block, 16 rows/wave -> 64 rows/block, grid 4096.
// No LDS: B-fragments read straight from bf16 W (L1/L2-resident, 32 KB).
__global__ __launch_bounds__(256, 5) void mobius_linear_kernel(
    const float* __restrict__ X,
    const unsigned short* __restrict__ Wb,
    const float* __restrict__ Bias,
    float* __restrict__ Out)
{
    const int tid  = threadIdx.x;
    const int wave = tid >> 6;
    const int lane = tid & 63;
    const int q = lane >> 4;     // quad
    const int c = lane & 15;     // A-row / B-col index within fragment

    const int rowbase = blockIdx.x * 64 + wave * 16;

    // ---- bias fragment (col = n*16 + c) and ||b||^2 ----
    float bias_f[8];
#pragma unroll
    for (int n = 0; n < 8; ++n) bias_f[n] = Bias[n * 16 + c];
    float b2 = 0.f;
#pragma unroll
    for (int n = 0; n < 8; ++n) b2 = fmaf(bias_f[n], bias_f[n], b2);
    b2 += __shfl_xor(b2, 1);
    b2 += __shfl_xor(b2, 2);
    b2 += __shfl_xor(b2, 4);
    b2 += __shfl_xor(b2, 8);

    // ---- A fragments: fp32 loads, ||x||^2 in fp32, pack bf16 ----
    short8 afrag[4];
    float xn2 = 0.f;
    const float* xrow = X + (size_t)(rowbase + c) * 128;
#pragma unroll
    for (int kc = 0; kc < 4; ++kc) {
        const float* src = xrow + kc * 32 + q * 8;
        floatx4 x0 = *reinterpret_cast<const floatx4*>(src);
        floatx4 x1 = *reinterpret_cast<const floatx4*>(src + 4);
        short8 pk;
#pragma unroll
        for (int j = 0; j < 4; ++j) {
            xn2 = fmaf(x0[j], x0[j], xn2);
            xn2 = fmaf(x1[j], x1[j], xn2);
            pk[j] = (short)f2b(x0[j]); pk[4 + j] = (short)f2b(x1[j]);
        }
        afrag[kc] = pk;
    }
    xn2 += __shfl_xor(xn2, 16);
    xn2 += __shfl_xor(xn2, 32);

    // ---- MFMA: Mx[16 rows][128 cols], B-frags straight from global ----
    floatx4 acc[8];
#pragma unroll
    for (int n = 0; n < 8; ++n) acc[n] = (floatx4){0.f, 0.f, 0.f, 0.f};

#pragma unroll
    for (int n = 0; n < 8; ++n) {
        const unsigned short* wrow = Wb + (n * 16 + c) * 128 + q * 8;
#pragma unroll
        for (int kc = 0; kc < 4; ++kc) {
            short8 bf = *reinterpret_cast<const short8*>(wrow + kc * 32);
            acc[n] = __builtin_amdgcn_mfma_f32_16x16x32_bf16(afrag[kc], bf, acc[n], 0, 0, 0);
        }
    }

    // ---- fused epilogue (C layout: col = n*16+c, row = q*4+r) ----
    float m2[4], mb[4];
#pragma unroll
    for (int r = 0; r < 4; ++r) {
        float s2 = 0.f, sb = 0.f;
#pragma unroll
        for (int n = 0; n < 8; ++n) {
            float v = acc[n][r];
            s2 = fmaf(v, v, s2);
            sb = fmaf(v, bias_f[n], sb);
        }
        m2[r] = s2; mb[r] = sb;
    }
#pragma unroll
    for (int r = 0; r < 4; ++r) {
        m2[r] += __shfl_xor(m2[r], 1); mb[r] += __shfl_xor(mb[r], 1);
        m2[r] += __shfl_xor(m2[r], 2); mb[r] += __shfl_xor(mb[r], 2);
        m2[r] += __shfl_xor(m2[r], 4); mb[r] += __shfl_xor(mb[r], 4);
        m2[r] += __shfl_xor(m2[r], 8); mb[r] += __shfl_xor(mb[r], 8);
    }
#pragma unroll
    for (int r = 0; r < 4; ++r) {
        float xr2   = __shfl(xn2, q * 4 + r);             // row scalar
        float xnorm = fmaxf(sqrtf(xr2), 1e-15f);
        float u     = fminf(xnorm, 1.f - 1e-7f);
        float at    = 0.5f * __logf((1.f + u) / (1.f - u));   // artanh
        float Mxn   = fmaxf(sqrtf(m2[r]), 1e-15f);
        float arg   = Mxn / xnorm * at;                        // >= 0
        float e     = __expf(2.f * arg);
        float th    = 1.f - 2.f / (e + 1.f);                   // tanh
        float scale = (Mxn <= 1e-10f) ? 0.f : th / Mxn;
        float y2 = scale * scale * m2[r];                      // ||y||^2
        float yb = scale * mb[r];                              // y.b
        float t1  = 1.f + 2.f * yb + b2;
        float den = fmaxf(fmaf(y2, b2, 1.f + 2.f * yb), 1e-15f);
        float Af = t1 * scale / den;        // z = Af*Mx + Bf*bias
        float Bf = (1.f - y2) / den;
        float zn2 = Af * Af * m2[r] + 2.f * Af * Bf * mb[r] + Bf * Bf * b2;
        float zn  = fmaxf(sqrtf(zn2), 1e-15f);
        const float maxn = 1.f - 1e-5f;
        float fac = (zn > maxn) ? (maxn / zn) : 1.f;
        Af *= fac; Bf *= fac;

        int row = rowbase + q * 4 + r;
        float* orow = Out + (size_t)row * 128;
#pragma unroll
        for (int n = 0; n < 8; ++n) {
            orow[n * 16 + c] = fmaf(Af, acc[n][r], Bf * bias_f[n]);
        }
    }
}

extern "C" void kernel_launch(void* const* d_in, const int* in_sizes, int n_in,
                              void* d_out, int out_size, void* d_ws, size_t ws_size,
                              hipStream_t stream) {
    const float* X    = (const float*)d_in[0];
    const float* W    = (const float*)d_in[1];
    const float* Bias = (const float*)d_in[2];
    float* Out = (float*)d_out;
    unsigned short* Wb = (unsigned short*)d_ws;   // 32 KB bf16 copy of W

    hipLaunchKernelGGL(convert_w_kernel, dim3(16), dim3(256), 0, stream, W, Wb);
    hipLaunchKernelGGL(mobius_linear_kernel, dim3(4096), dim3(256), 0, stream,
                       X, Wb, Bias, Out);
}

// Round 4
// 258.986 us; speedup vs baseline: 1.0707x; 1.0707x over previous
//
#include <hip/hip_runtime.h>

typedef __attribute__((ext_vector_type(8))) short short8;
typedef __attribute__((ext_vector_type(4))) short short4v;
typedef __attribute__((ext_vector_type(4))) int   int4v;
typedef __attribute__((ext_vector_type(4))) float floatx4;

__device__ __forceinline__ unsigned short f2b(float f) {
    union { float f; unsigned int i; } v; v.f = f;
    unsigned int u = v.i;
    u += 0x7FFFu + ((u >> 16) & 1u);   // RNE
    return (unsigned short)(u >> 16);
}

// pack two fp32 -> bf16x2 dword (round-half-up via +0x8000, then v_perm)
__device__ __forceinline__ int pack2(float f0, float f1) {
    unsigned int u0 = __float_as_uint(f0) + 0x8000u;
    unsigned int u1 = __float_as_uint(f1) + 0x8000u;
    return (int)__builtin_amdgcn_perm(u1, u0, 0x07060302u); // {u0.hi16, u1.hi16}
}

// ---- kernel 1: W fp32 -> bf16 into workspace (16384 elements) ----
__global__ __launch_bounds__(256) void convert_w_kernel(
    const float* __restrict__ W, unsigned short* __restrict__ Wb)
{
    int i = (blockIdx.x * 256 + threadIdx.x) * 4;
    floatx4 w = *reinterpret_cast<const floatx4*>(W + i);
    short4v p;
#pragma unroll
    for (int j = 0; j < 4; ++j) p[j] = (short)f2b(w[j]);
    *reinterpret_cast<short4v*>(Wb + i) = p;
}

// ---- kernel 2: fused mobius linear ----
// 4 waves x 32 rows = 128 rows/block, grid 2048.
// B-tile n frag-lane c holds W row (c*8+n)  => lane owns output cols c*8..c*8+7
// => stores are 2x dwordx4/row, each instruction = 4 full 512B row segments.
// W staged bf16 in LDS, swizzled: chunk s = (j + (row>>3)) & 15 -> banks uniform.
__global__ __launch_bounds__(256, 4) void mobius_linear_kernel(
    const float* __restrict__ X,
    const unsigned short* __restrict__ Wb,
    const float* __restrict__ Bias,
    float* __restrict__ Out)
{
    __shared__ unsigned short ldsW[128 * 128];   // 32 KB

    const int tid  = threadIdx.x;
    const int wave = tid >> 6;
    const int lane = tid & 63;
    const int q = lane >> 4;     // quad
    const int c = lane & 15;     // frag index

    // ---- stage pre-converted W into LDS (swizzled), 128 B/thread ----
#pragma unroll
    for (int i = 0; i < 8; ++i) {
        int chunk = i * 256 + tid;          // 0..2047
        int row = chunk >> 4, j = chunk & 15;
        short8 v = *reinterpret_cast<const short8*>(Wb + row * 128 + j * 8);
        int s = (j + (row >> 3)) & 15;
        *reinterpret_cast<short8*>(&ldsW[row * 128 + s * 8]) = v;
    }

    const int rowbase = blockIdx.x * 128 + wave * 32;

    // ---- A fragments: fp32 loads, ||x||^2 in fp32, pack bf16 via perm ----
    short8 afrag[2][4];
    float xn2[2] = {0.f, 0.f};
#pragma unroll
    for (int g = 0; g < 2; ++g) {
        const float* xrow = X + (size_t)(rowbase + g * 16 + c) * 128;
#pragma unroll
        for (int kc = 0; kc < 4; ++kc) {
            const float* src = xrow + kc * 32 + q * 8;
            floatx4 x0 = *reinterpret_cast<const floatx4*>(src);
            floatx4 x1 = *reinterpret_cast<const floatx4*>(src + 4);
#pragma unroll
            for (int j = 0; j < 4; ++j) {
                xn2[g] = fmaf(x0[j], x0[j], xn2[g]);
                xn2[g] = fmaf(x1[j], x1[j], xn2[g]);
            }
            int4v pk;
            pk[0] = pack2(x0[0], x0[1]); pk[1] = pack2(x0[2], x0[3]);
            pk[2] = pack2(x1[0], x1[1]); pk[3] = pack2(x1[2], x1[3]);
            union { int4v i; short8 s; } u; u.i = pk;
            afrag[g][kc] = u.s;
        }
    }
    xn2[0] += __shfl_xor(xn2[0], 16); xn2[0] += __shfl_xor(xn2[0], 32);
    xn2[1] += __shfl_xor(xn2[1], 16); xn2[1] += __shfl_xor(xn2[1], 32);

    // ---- bias fragment: lane owns cols c*8..c*8+7 (2x float4) ----
    floatx4 blo = *reinterpret_cast<const floatx4*>(Bias + c * 8);
    floatx4 bhi = *reinterpret_cast<const floatx4*>(Bias + c * 8 + 4);
    float bias_f[8];
#pragma unroll
    for (int j = 0; j < 4; ++j) { bias_f[j] = blo[j]; bias_f[4 + j] = bhi[j]; }
    float b2 = 0.f;
#pragma unroll
    for (int n = 0; n < 8; ++n) b2 = fmaf(bias_f[n], bias_f[n], b2);
    b2 += __shfl_xor(b2, 1);
    b2 += __shfl_xor(b2, 2);
    b2 += __shfl_xor(b2, 4);
    b2 += __shfl_xor(b2, 8);

    __syncthreads();

    // ---- MFMA: Mx[32 rows][128 cols]; B-frag tile n = W rows {c*8+n} ----
    floatx4 acc[2][8];
#pragma unroll
    for (int g = 0; g < 2; ++g)
#pragma unroll
        for (int n = 0; n < 8; ++n)
            acc[g][n] = (floatx4){0.f, 0.f, 0.f, 0.f};

#pragma unroll
    for (int kc = 0; kc < 4; ++kc) {
        const int s8 = ((kc * 4 + q + c) & 15) * 8;   // swizzled chunk offset
#pragma unroll
        for (int n = 0; n < 8; ++n) {
            short8 bf = *reinterpret_cast<const short8*>(
                &ldsW[(c * 8 + n) * 128 + s8]);
            acc[0][n] = __builtin_amdgcn_mfma_f32_16x16x32_bf16(afrag[0][kc], bf, acc[0][n], 0, 0, 0);
            acc[1][n] = __builtin_amdgcn_mfma_f32_16x16x32_bf16(afrag[1][kc], bf, acc[1][n], 0, 0, 0);
        }
    }

    // ---- fused epilogue (C layout: phys col = c*8+n, row = g*16+q*4+r) ----
#pragma unroll
    for (int g = 0; g < 2; ++g) {
        float m2[4], mb[4];
#pragma unroll
        for (int r = 0; r < 4; ++r) {
            float s2 = 0.f, sb = 0.f;
#pragma unroll
            for (int n = 0; n < 8; ++n) {
                float v = acc[g][n][r];
                s2 = fmaf(v, v, s2);
                sb = fmaf(v, bias_f[n], sb);
            }
            m2[r] = s2; mb[r] = sb;
        }
#pragma unroll
        for (int r = 0; r < 4; ++r) {
            m2[r] += __shfl_xor(m2[r], 1); mb[r] += __shfl_xor(mb[r], 1);
            m2[r] += __shfl_xor(m2[r], 2); mb[r] += __shfl_xor(mb[r], 2);
            m2[r] += __shfl_xor(m2[r], 4); mb[r] += __shfl_xor(mb[r], 4);
            m2[r] += __shfl_xor(m2[r], 8); mb[r] += __shfl_xor(mb[r], 8);
        }
#pragma unroll
        for (int r = 0; r < 4; ++r) {
            float xr2   = __shfl(xn2[g], q * 4 + r);          // row scalar
            float xnorm = fmaxf(sqrtf(xr2), 1e-15f);
            float u     = fminf(xnorm, 1.f - 1e-7f);
            float at    = 0.5f * __logf((1.f + u) / (1.f - u));   // artanh
            float Mxn   = fmaxf(sqrtf(m2[r]), 1e-15f);
            float arg   = Mxn / xnorm * at;                        // >= 0
            float e     = __expf(2.f * arg);
            float th    = 1.f - 2.f / (e + 1.f);                   // tanh
            float scale = (Mxn <= 1e-10f) ? 0.f : th / Mxn;
            float y2 = scale * scale * m2[r];                      // ||y||^2
            float yb = scale * mb[r];                              // y.b
            float t1  = 1.f + 2.f * yb + b2;
            float den = fmaxf(fmaf(y2, b2, 1.f + 2.f * yb), 1e-15f);
            float Af = t1 * scale / den;        // z = Af*Mx + Bf*bias
            float Bf = (1.f - y2) / den;
            float zn2 = Af * Af * m2[r] + 2.f * Af * Bf * mb[r] + Bf * Bf * b2;
            float zn  = fmaxf(sqrtf(zn2), 1e-15f);
            const float maxn = 1.f - 1e-5f;
            float fac = (zn > maxn) ? (maxn / zn) : 1.f;
            Af *= fac; Bf *= fac;

            int row = rowbase + g * 16 + q * 4 + r;
            float* orow = Out + (size_t)row * 128 + c * 8;
            floatx4 lo, hi;
#pragma unroll
            for (int n = 0; n < 4; ++n) {
                lo[n] = fmaf(Af, acc[g][n][r],     Bf * bias_f[n]);
                hi[n] = fmaf(Af, acc[g][4 + n][r], Bf * bias_f[4 + n]);
            }
            *reinterpret_cast<floatx4*>(orow)     = lo;
            *reinterpret_cast<floatx4*>(orow + 4) = hi;
        }
    }
}

extern "C" void kernel_launch(void* const* d_in, const int* in_sizes, int n_in,
                              void* d_out, int out_size, void* d_ws, size_t ws_size,
                              hipStream_t stream) {
    const float* X    = (const float*)d_in[0];
    const float* W    = (const float*)d_in[1];
    const float* Bias = (const float*)d_in[2];
    float* Out = (float*)d_out;
    unsigned short* Wb = (unsigned short*)d_ws;   // 32 KB bf16 copy of W

    hipLaunchKernelGGL(convert_w_kernel, dim3(16), dim3(256), 0, stream, W, Wb);
    hipLaunchKernelGGL(mobius_linear_kernel, dim3(2048), dim3(256), 0, stream,
                       X, Wb, Bias, Out);
}